// Round 1
// baseline (340.105 us; speedup 1.0000x reference)
//
#include <hip/hip_runtime.h>

// Problem constants (from reference setup_inputs):
//   x: (B=2, C=1, T=2000) fp32 ; W: (L=101, K=200) fp32
//   out[b,c,t,k,l] = x_pad[b,c,t+k] * W[l,k]  -> (2,1,2000,200,101) fp32
#define B_    2
#define T_    2000
#define K_    200
#define L_    101
#define ROW_  (K_ * L_)      // 20200 elements per (b,t) row
#define ROW4_ (ROW_ / 4)     // 5050 float4 per row (20200 % 4 == 0)
#define XP_   (T_ + K_)      // 2200 padded x length per batch

// ---- setup: transpose W -> Wt[k*L + l], pad x -> xp[b][0..XP_) ----
__global__ __launch_bounds__(256) void prep_kernel(const float* __restrict__ x,
                                                   const float* __restrict__ W,
                                                   float* __restrict__ Wt,
                                                   float* __restrict__ xp) {
    int tid = blockIdx.x * 256 + threadIdx.x;
    if (tid < ROW_) {
        int l = tid / K_;             // W is (L, K) row-major
        int k = tid - l * K_;
        Wt[k * L_ + l] = W[tid];      // Wt is (K, L): matches output inner layout
    }
    if (tid < B_ * XP_) {
        int b  = tid / XP_;
        int tt = tid - b * XP_;
        xp[tid] = (tt < T_) ? x[b * T_ + tt] : 0.0f;
    }
}

// ---- main: one block per output row (b*T + t), float4 streaming stores ----
__global__ __launch_bounds__(256) void expand_kernel(const float* __restrict__ xp,
                                                     const float* __restrict__ Wt,
                                                     float* __restrict__ out) {
    const int row = blockIdx.x;                 // row = b*T_ + t, 0..3999
    const unsigned b = (unsigned)row / (unsigned)T_;   // magic-mul, once per block
    const int t = row - (int)b * T_;
    const float* __restrict__ xrow = xp + b * XP_ + t; // xrow[k] = x_pad[b, t+k]
    float4* __restrict__ orow = (float4*)(out + (size_t)row * ROW_); // 80800B stride, 16B-aligned
    const float4* __restrict__ w4 = (const float4*)Wt;

    for (int j4 = threadIdx.x; j4 < ROW4_; j4 += 256) {
        float4 w = w4[j4];                      // coalesced, L1/L2-resident
        int j = j4 * 4;                         // j = k*101 + l
        unsigned k0 = (unsigned)(j + 0) / (unsigned)L_;  // magic-mul by 101
        unsigned k1 = (unsigned)(j + 1) / (unsigned)L_;
        unsigned k2 = (unsigned)(j + 2) / (unsigned)L_;
        unsigned k3 = (unsigned)(j + 3) / (unsigned)L_;
        float4 r;
        r.x = w.x * xrow[k0];                   // near-broadcast loads (~3 lines/wave)
        r.y = w.y * xrow[k1];
        r.z = w.z * xrow[k2];
        r.w = w.w * xrow[k3];
        orow[j4] = r;                           // coalesced 16B store
    }
}

// ---- fallback (no workspace): direct reads, bounds-checked ----
__global__ __launch_bounds__(256) void expand_fallback(const float* __restrict__ x,
                                                       const float* __restrict__ W,
                                                       float* __restrict__ out) {
    const int row = blockIdx.x;
    const unsigned b = (unsigned)row / (unsigned)T_;
    const int t = row - (int)b * T_;
    const float* __restrict__ xb = x + b * T_;
    float* __restrict__ orow = out + (size_t)row * ROW_;
    for (int j = threadIdx.x; j < ROW_; j += 256) {
        unsigned k = (unsigned)j / (unsigned)L_;
        unsigned l = (unsigned)j - k * (unsigned)L_;
        float xv = (t + (int)k < T_) ? xb[t + k] : 0.0f;
        orow[j] = xv * W[l * K_ + k];
    }
}

extern "C" void kernel_launch(void* const* d_in, const int* in_sizes, int n_in,
                              void* d_out, int out_size, void* d_ws, size_t ws_size,
                              hipStream_t stream) {
    const float* x = (const float*)d_in[0];   // (B, C=1, T) fp32
    const float* W = (const float*)d_in[1];   // (L, K) fp32
    float* out = (float*)d_out;               // (B, 1, T, K, L) fp32

    const size_t ws_needed = (size_t)(ROW_ + B_ * XP_) * sizeof(float); // 98,400 B
    if (ws_size >= ws_needed && d_ws != nullptr) {
        float* Wt = (float*)d_ws;             // 20200 floats, 16B-aligned
        float* xp = Wt + ROW_;                // offset 80800 B, still 16B-aligned
        prep_kernel<<<(ROW_ + 255) / 256, 256, 0, stream>>>(x, W, Wt, xp);
        expand_kernel<<<B_ * T_, 256, 0, stream>>>(xp, Wt, out);
    } else {
        expand_fallback<<<B_ * T_, 256, 0, stream>>>(x, W, out);
    }
}